// Round 16
// baseline (171.930 us; speedup 1.0000x reference)
//
#include <hip/hip_runtime.h>
#include <hip/hip_bf16.h>

#define NROW 131072   // B*L
#define D 256
#define K 320
#define BN_EPS 1e-5f
#define FIXSCALE 16777216.0f   // 2^24 fixed-point for deterministic atomics

typedef _Float16 half8 __attribute__((ext_vector_type(8)));
typedef float f32x4 __attribute__((ext_vector_type(4)));
typedef __attribute__((address_space(3))) unsigned int lds_u32;
typedef __attribute__((address_space(1))) const unsigned int g_u32;

// ws layout:
//   u64 acc[512]   @ 0      (4 KB)
//   f32 meanb[256] @ 4096
//   f32 rsb[256]   @ 5120
//   f32 cnorm[320] @ 6144
//   f16 cbx        @ 8192   (320 KB) codebook fragments:
//     tile nt(0..19) = 16 codes, hl(0=hi,1=lo), ks(0..7):
//     halfs at ((nt*2+hl)*8+ks)*512 + lane*8  -> tile nt = 16 KB at nt*16384 B

// ---------------- kernel 1: per-block channel partials -> fixed-point atomics
__global__ __launch_bounds__(256) void k_stats_partial(const float* __restrict__ x,
                                                       unsigned long long* __restrict__ acc) {
  const int d = threadIdx.x;
  const int blk = blockIdx.x;         // 512 blocks, 256 rows each
  const float* p = x + (size_t)blk * 256 * D + d;
  float s = 0.f, q = 0.f;
  #pragma unroll 4
  for (int r = 0; r < 256; ++r) {
    float v = p[(size_t)r * D];
    s += v;
    q = fmaf(v, v, q);
  }
  long long si = llrintf(s * FIXSCALE);
  long long qi = llrintf(q * FIXSCALE);
  atomicAdd(&acc[d],       (unsigned long long)si);
  atomicAdd(&acc[256 + d], (unsigned long long)qi);
}

// ---------------- kernel 2: finalize stats + codebook norms -----------------
__global__ __launch_bounds__(256) void k_stats_final(const unsigned long long* __restrict__ acc,
                                                     const float* __restrict__ cb,
                                                     float* __restrict__ meanb,
                                                     float* __restrict__ rsb,
                                                     float* __restrict__ cnorm) {
  const int t = threadIdx.x;
  if (blockIdx.x == 0) {
    double s = (double)(long long)acc[t]       / (double)FIXSCALE;
    double q = (double)(long long)acc[256 + t] / (double)FIXSCALE;
    double mean = s / (double)NROW;
    double var  = q / (double)NROW - mean * mean;
    meanb[t] = (float)mean;
    rsb[t]   = (float)(1.0 / sqrt(var + (double)BN_EPS));
  } else {
    for (int code = t; code < K; code += 256) {
      const float* c = cb + (size_t)code * D;
      float s = 0.f;
      for (int dd = 0; dd < D; ++dd) s = fmaf(c[dd], c[dd], s);
      cnorm[code] = s;
    }
  }
}

// ---------------- kernel 2b: split codebook to fp16 hi/lo fragments ---------
// blocks 0..159: MFMA B-fragment prep (nt = b>>3, ks = b&7):
//   lane l holds code = nt*16 + (l&15), k = ks*32 + (l>>4)*8..+8
// block 160: zero the fixed-point stat accumulators
__global__ __launch_bounds__(64) void k_cbprep(const float* __restrict__ cb,
                                               _Float16* __restrict__ cbx,
                                               unsigned long long* __restrict__ acc) {
  const int b = blockIdx.x;
  const int l = threadIdx.x;
  if (b == 160) {
    #pragma unroll
    for (int j = 0; j < 8; ++j) acc[j * 64 + l] = 0ull;
    return;
  }
  const int nt = b >> 3;
  const int ks = b & 7;
  const int code = nt * 16 + (l & 15);
  const int d0 = ks * 32 + (l >> 4) * 8;
  const float* src = cb + (size_t)code * D + d0;
  const size_t bh = ((size_t)(nt * 2 + 0) * 8 + ks) * 512 + l * 8;
  const size_t bl = ((size_t)(nt * 2 + 1) * 8 + ks) * 512 + l * 8;
  #pragma unroll
  for (int j = 0; j < 8; ++j) {
    float v = src[j];
    _Float16 h = (_Float16)v;
    _Float16 lo = (_Float16)(v - (float)h);
    cbx[bh + j] = h;
    cbx[bl + j] = lo;
  }
}

// ---------------- kernel 3: R14 structure + global_load_lds B staging -------
// 2048 blocks x 256 thr (4 waves x 16 rows). Wave wv owns rows row0+wv*16..+16
// vs ALL 320 codes. Chunk = 16 codes (16 KB), 2 LDS slots; B staged by
// direct global->LDS DMA (no staging regs, no ds_write port traffic).
__global__ __launch_bounds__(256) void k_main(const float* __restrict__ x,
                                              const float* __restrict__ w,
                                              const float* __restrict__ bias,
                                              const float* __restrict__ cb,
                                              const float* __restrict__ meanb,
                                              const float* __restrict__ rsb,
                                              const float* __restrict__ cnorm,
                                              const _Float16* __restrict__ cbx,
                                              float* __restrict__ out) {
  __shared__ _Float16 Bbuf[2][8192];    // 2 x 16 KB chunk slots
  __shared__ float sxs[64];             // per-row |xb|^2
  __shared__ int bsel[64];

  const int t = threadIdx.x;
  const int lane = t & 63;
  const int wv = t >> 6;              // wave 0..3
  const int c15 = lane & 15;
  const int g = lane >> 4;
  const int row0 = (int)blockIdx.x * 64;

  // ---- staging: wave wv DMAs its 4 KB quarter of the 16 KB chunk ----
  // LDS dest is lane-linear (base + lane*16) as global_load_lds requires;
  // cbx chunk layout is contiguous so the copy is a straight memcpy.
#define ISSUE(c) {                                                            \
    const char* gp_ = (const char*)cbx + (size_t)(c) * 16384 + wv * 4096      \
                      + (size_t)lane * 16;                                    \
    _Float16* lp_ = Bbuf[(c) & 1] + wv * 2048 + lane * 8;                     \
    __builtin_amdgcn_global_load_lds((g_u32*)(gp_),        (lds_u32*)(lp_),         16, 0, 0); \
    __builtin_amdgcn_global_load_lds((g_u32*)(gp_ + 1024), (lds_u32*)(lp_ + 512),   16, 0, 0); \
    __builtin_amdgcn_global_load_lds((g_u32*)(gp_ + 2048), (lds_u32*)(lp_ + 1024),  16, 0, 0); \
    __builtin_amdgcn_global_load_lds((g_u32*)(gp_ + 3072), (lds_u32*)(lp_ + 1536),  16, 0, 0); \
  }

  ISSUE(0);                           // chunk0 DMA flies under A-prep

  // ---- x -> A fragments in registers (normalize + fp16 hi/lo split) ----
  // lane l: row = row0 + wv*16 + (l&15), k-elems (l>>4)*8 + ks*32 .. +8
  half8 ah[8], al[8];
  float accq = 0.f;
  {
    const int arow = row0 + wv * 16 + c15;
    const int dbase = g * 8;
    const float* xp = x + (size_t)arow * D + dbase;
    #pragma unroll
    for (int ks = 0; ks < 8; ++ks) {
      const int d0 = dbase + ks * 32;
      float4 xa = *(const float4*)(xp + ks * 32);
      float4 xb2 = *(const float4*)(xp + ks * 32 + 4);
      float4 m0 = *(const float4*)(meanb + d0);
      float4 m1 = *(const float4*)(meanb + d0 + 4);
      float4 r0 = *(const float4*)(rsb + d0);
      float4 r1 = *(const float4*)(rsb + d0 + 4);
      float4 w0 = *(const float4*)(w + d0);
      float4 w1 = *(const float4*)(w + d0 + 4);
      float4 b0 = *(const float4*)(bias + d0);
      float4 b1 = *(const float4*)(bias + d0 + 4);
      float o0 = ((xa.x - m0.x) * r0.x) * w0.x + b0.x;
      float o1 = ((xa.y - m0.y) * r0.y) * w0.y + b0.y;
      float o2 = ((xa.z - m0.z) * r0.z) * w0.z + b0.z;
      float o3 = ((xa.w - m0.w) * r0.w) * w0.w + b0.w;
      float o4 = ((xb2.x - m1.x) * r1.x) * w1.x + b1.x;
      float o5 = ((xb2.y - m1.y) * r1.y) * w1.y + b1.y;
      float o6 = ((xb2.z - m1.z) * r1.z) * w1.z + b1.z;
      float o7 = ((xb2.w - m1.w) * r1.w) * w1.w + b1.w;
      accq = fmaf(o0, o0, accq); accq = fmaf(o1, o1, accq);
      accq = fmaf(o2, o2, accq); accq = fmaf(o3, o3, accq);
      accq = fmaf(o4, o4, accq); accq = fmaf(o5, o5, accq);
      accq = fmaf(o6, o6, accq); accq = fmaf(o7, o7, accq);
      _Float16 h;
      h = (_Float16)o0; ah[ks][0] = h; al[ks][0] = (_Float16)(o0 - (float)h);
      h = (_Float16)o1; ah[ks][1] = h; al[ks][1] = (_Float16)(o1 - (float)h);
      h = (_Float16)o2; ah[ks][2] = h; al[ks][2] = (_Float16)(o2 - (float)h);
      h = (_Float16)o3; ah[ks][3] = h; al[ks][3] = (_Float16)(o3 - (float)h);
      h = (_Float16)o4; ah[ks][4] = h; al[ks][4] = (_Float16)(o4 - (float)h);
      h = (_Float16)o5; ah[ks][5] = h; al[ks][5] = (_Float16)(o5 - (float)h);
      h = (_Float16)o6; ah[ks][6] = h; al[ks][6] = (_Float16)(o6 - (float)h);
      h = (_Float16)o7; ah[ks][7] = h; al[ks][7] = (_Float16)(o7 - (float)h);
    }
  }

  // row sum: butterfly over the 4 k-slices (lanes xor 16, 32); deterministic
  {
    float v1 = accq + __shfl_xor(accq, 16);
    float sxrow = v1 + __shfl_xor(v1, 32);
    if (lane < 16) sxs[wv * 16 + lane] = sxrow;
  }
  __syncthreads();                    // drains vmcnt: chunk0 landed; sxs visible

  // ---- chunk loop: 20 x (16 codes); argmin folded per chunk ----
  float bv[4];
  int   bix[4];
  #pragma unroll
  for (int r = 0; r < 4; ++r) { bv[r] = 3.4e38f; bix[r] = 0x7fffffff; }

  float sxr[4];
  #pragma unroll
  for (int r = 0; r < 4; ++r) sxr[r] = sxs[wv * 16 + g * 4 + r];

  for (int c = 0; c < 20; ++c) {
    // DMA chunk c+1 into slot (c+1)&1: that slot's readers (chunk c-1)
    // finished before the barrier we just crossed.
    if (c + 1 < 20) ISSUE(c + 1);

    // COMPUTE chunk c from slot c&1 (landed: issued last iter, drained at
    // the barrier)
    {
      const _Float16* bb = Bbuf[c & 1] + lane * 8;
      f32x4 acc = (f32x4){0.f, 0.f, 0.f, 0.f};
      #pragma unroll
      for (int ks = 0; ks < 8; ++ks) {
        half8 bh = *(const half8*)(bb + ks * 512);          // hl=0
        half8 bl = *(const half8*)(bb + 4096 + ks * 512);   // hl=1
        acc = __builtin_amdgcn_mfma_f32_16x16x32_f16(ah[ks], bh, acc, 0, 0, 0);
        acc = __builtin_amdgcn_mfma_f32_16x16x32_f16(ah[ks], bl, acc, 0, 0, 0);
        acc = __builtin_amdgcn_mfma_f32_16x16x32_f16(al[ks], bh, acc, 0, 0, 0);
      }
      // d2 = (sx - 2*dot) + cn  (exact rounding-matched expression)
      // C/D layout: col = lane&15 (code), row = (lane>>4)*4 + r
      const int code = c * 16 + c15;
      const float cn = cnorm[code];
      #pragma unroll
      for (int r = 0; r < 4; ++r) {
        const float d2 = (sxr[r] - 2.0f * acc[r]) + cn;
        if (d2 < bv[r] || (d2 == bv[r] && code < bix[r])) { bv[r] = d2; bix[r] = code; }
      }
    }
    if (c < 19) __syncthreads();      // drains DMA: chunk c+1 ready
  }

  // ---- butterfly argmin across the 16 lanes (columns) ----
  #pragma unroll
  for (int off = 8; off >= 1; off >>= 1) {
    #pragma unroll
    for (int r = 0; r < 4; ++r) {
      const float ov = __shfl_xor(bv[r], off);
      const int   oi = __shfl_xor(bix[r], off);
      if (ov < bv[r] || (ov == bv[r] && oi < bix[r])) { bv[r] = ov; bix[r] = oi; }
    }
  }
  if (c15 == 0) {
    #pragma unroll
    for (int r = 0; r < 4; ++r) {
      const int row = wv * 16 + g * 4 + r;     // local row 0..63
      bsel[row] = bix[r];
      out[(size_t)NROW * D + row0 + row] = (float)bix[r];
    }
  }
  __syncthreads();

  // ---- gather chosen codes (exact f32 copy), 4 threads per row ----
  {
    const int lr = t >> 2;            // 0..63
    const int q = t & 3;
    const int code = bsel[lr];
    const float* cp = cb + (size_t)code * D;
    float* op = out + (size_t)(row0 + lr) * D;
    #pragma unroll
    for (int e = 0; e < 16; ++e) {
      *(float4*)(op + e * 16 + q * 4) = *(const float4*)(cp + e * 16 + q * 4);
    }
  }
#undef ISSUE
}

extern "C" void kernel_launch(void* const* d_in, const int* in_sizes, int n_in,
                              void* d_out, int out_size, void* d_ws, size_t ws_size,
                              hipStream_t stream) {
  const float* x    = (const float*)d_in[0];
  const float* w    = (const float*)d_in[1];
  const float* bias = (const float*)d_in[2];
  const float* cb   = (const float*)d_in[3];
  float* out = (float*)d_out;

  unsigned long long* acc = (unsigned long long*)d_ws;
  float* meanb = (float*)((char*)d_ws + 4096);
  float* rsb   = meanb + 256;
  float* cnorm = rsb + 256;
  _Float16* cbx = (_Float16*)((char*)d_ws + 8192);   // 320 KB

  k_cbprep<<<161, 64, 0, stream>>>(cb, cbx, acc);    // prep + zero (merged)
  k_stats_partial<<<512, 256, 0, stream>>>(x, acc);
  k_stats_final<<<2, 256, 0, stream>>>(acc, cb, meanb, rsb, cnorm);
  k_main<<<NROW / 64, 256, 0, stream>>>(x, w, bias, cb, meanb, rsb, cnorm, cbx, out);
}